// Round 6
// baseline (229.941 us; speedup 1.0000x reference)
//
#include <hip/hip_runtime.h>
#include <hip/hip_bf16.h>
#include <math.h>

// Problem constants: B=4, L=1024, D=512, H=8, C=8, Dk=64
#define NB 4
#define NL 1024
#define ND 512
#define NH 8
#define NC 8
#define NDK 64

static constexpr float KL3_CONST = 115.36544595161891f; // -0.5*(1+ln0.01)*64, per clustering call

typedef __bf16 bf16x8 __attribute__((ext_vector_type(8)));
typedef float  f32x4v __attribute__((ext_vector_type(4)));
typedef unsigned short u16x4 __attribute__((ext_vector_type(4)));
typedef unsigned short u16x8 __attribute__((ext_vector_type(8)));

__device__ __forceinline__ unsigned short bf16u(float f) {
    return __builtin_bit_cast(unsigned short, (__bf16)f);
}

// ---------------------------------------------------------------------------
// Clustering: probs, per-block kl/div partials, per-block Gram partials, and
// bf16 copies of query/key (data already in registers).
// grid: (8, 32, 2)  block: 128  (2 waves/SIMD chip-wide)
// ---------------------------------------------------------------------------
__global__ __launch_bounds__(128) void cluster_kernel(
    const float* __restrict__ query, const float* __restrict__ key,
    const float* __restrict__ tok_mu, const float* __restrict__ tok_log_var,
    const float* __restrict__ tok_log_prior,
    float* __restrict__ probs_q, float* __restrict__ probs_k,
    unsigned short* __restrict__ q16i, unsigned short* __restrict__ k16i,
    float* __restrict__ klp, float* __restrict__ divp, float* __restrict__ Gp)
{
    const int tid  = threadIdx.x;
    const int bh   = blockIdx.y;
    const int b    = bh >> 3, h = bh & 7;
    const int side = blockIdx.z;
    const int blocklin = side * 256 + bh * 8 + blockIdx.x;
    const float* src = side ? key : query;
    float* probs_out = side ? probs_k : probs_q;
    unsigned short* x16 = side ? k16i : q16i;

    __shared__ alignas(16) float mu_s[512];
    __shared__ alignas(16) float iv_s[512];
    __shared__ float lvsum_s[8], alpha_s[8], logp_s[8], prior_s[8];
    __shared__ float Pl[128 * 9];
    __shared__ float Gpart[2][64];
    __shared__ float red_s[4];

    for (int i = tid; i < 512; i += 128) {
        mu_s[i] = tok_mu[h * 512 + i];
        float lv = tok_log_var[h * 512 + i];
        iv_s[i] = __expf(-lv);
    }
    if (tid < 8) {
        float ls = 0.f, al = 0.f;
        for (int d = 0; d < 64; ++d) {
            float lv = tok_log_var[(h * 8 + tid) * 64 + d];
            ls += lv;
            al += 0.01f * __expf(-lv) + lv;
        }
        lvsum_s[tid] = ls; alpha_s[tid] = al;
    }
    if (tid == 0) {
        float lp[8]; float mx = -1e30f;
        for (int c = 0; c < 8; ++c) { lp[c] = tok_log_prior[h * 8 + c]; mx = fmaxf(mx, lp[c]); }
        float se = 0.f;
        for (int c = 0; c < 8; ++c) se += __expf(lp[c] - mx);
        float lse = mx + __logf(se);
        for (int c = 0; c < 8; ++c) { logp_s[c] = lp[c] - lse; prior_s[c] = __expf(lp[c] - lse); }
    }
    __syncthreads();

    const int l = blockIdx.x * 128 + tid;
    const float4* xp = (const float4*)(src + ((size_t)(b * NL + l)) * ND + h * NDK);
    float4 xr[16];
#pragma unroll
    for (int i = 0; i < 16; ++i) xr[i] = xp[i];

    // bf16 emit of this thread's h-slice (row l, dims h*64..h*64+63)
    {
        unsigned short* dst = x16 + ((size_t)(b * NL + l)) * ND + h * NDK;
#pragma unroll
        for (int i2 = 0; i2 < 8; ++i2) {
            float4 a = xr[2 * i2], c2 = xr[2 * i2 + 1];
            u16x8 o = { bf16u(a.x), bf16u(a.y), bf16u(a.z), bf16u(a.w),
                        bf16u(c2.x), bf16u(c2.y), bf16u(c2.z), bf16u(c2.w) };
            *(u16x8*)(dst + i2 * 8) = o;
        }
    }

    float ms[8];
#pragma unroll
    for (int c = 0; c < 8; ++c) {
        const float4* mc = (const float4*)(mu_s + c * 64);
        const float4* ic = (const float4*)(iv_s + c * 64);
        float s = 0.f;
#pragma unroll
        for (int i = 0; i < 16; ++i) {
            float4 m4 = mc[i], v4 = ic[i], x4 = xr[i];
            float dx = x4.x - m4.x; s = fmaf(dx * dx, v4.x, s);
            float dy = x4.y - m4.y; s = fmaf(dy * dy, v4.y, s);
            float dz = x4.z - m4.z; s = fmaf(dz * dz, v4.z, s);
            float dw = x4.w - m4.w; s = fmaf(dw * dw, v4.w, s);
        }
        ms[c] = s;
    }

    float lpdf[8]; float mx = -1e30f;
#pragma unroll
    for (int c = 0; c < 8; ++c) {
        lpdf[c] = -0.5f * (ms[c] + lvsum_s[c]) + logp_s[c];
        mx = fmaxf(mx, lpdf[c]);
    }
    float e[8]; float se = 0.f;
#pragma unroll
    for (int c = 0; c < 8; ++c) { e[c] = __expf(lpdf[c] - mx); se += e[c]; }
    float lse = __logf(se);
    float inv = 1.f / se;
    float p[8]; float kl1 = 0.f, kl2 = 0.f, sqq = 0.f;
#pragma unroll
    for (int c = 0; c < 8; ++c) {
        p[c] = e[c] * inv;
        float logprob = lpdf[c] - mx - lse;
        kl1 += prior_s[c] * (logp_s[c] - logprob);
        kl2 += p[c] * (ms[c] + alpha_s[c]);
        sqq = fmaf(p[c], p[c], sqq);
    }

    float* po = probs_out + ((size_t)((b * NH + h) * NL + l)) * NC;
    ((float4*)po)[0] = make_float4(p[0], p[1], p[2], p[3]);
    ((float4*)po)[1] = make_float4(p[4], p[5], p[6], p[7]);
#pragma unroll
    for (int c = 0; c < 8; ++c) Pl[tid * 9 + c] = p[c];

    float dterm = 1.25f * (sqq - 1.f) * (sqq - 1.f) - 0.75f * sqq * sqq;
    float klv = kl1 + 0.5f * kl2;
    __syncthreads();

    // Gram partials over this block's 128 rows (2 halves of 64)
    {
        int qt = tid >> 6, pos = tid & 63, c1 = pos >> 3, c2 = pos & 7;
        float g = 0.f;
        for (int i = 0; i < 64; ++i) {
            int ll = qt * 64 + i;
            g = fmaf(Pl[ll * 9 + c1], Pl[ll * 9 + c2], g);
        }
        Gpart[qt][pos] = g;
    }

#pragma unroll
    for (int o = 32; o > 0; o >>= 1) {
        klv   += __shfl_down(klv, o);
        dterm += __shfl_down(dterm, o);
    }
    if ((tid & 63) == 0) { red_s[tid >> 6] = klv; red_s[2 + (tid >> 6)] = dterm; }
    __syncthreads();
    if (tid == 0) {
        klp[blocklin]  = red_s[0] + red_s[1];
        divp[blocklin] = red_s[2] + red_s[3];
    }
    if (tid < 64) Gp[(size_t)blocklin * 64 + tid] = Gpart[0][tid] + Gpart[1][tid];
}

// ---------------------------------------------------------------------------
// bf16 MFMA GEMM with register prefetch of the next k-tile.
// out[row][col] = (Sum_k A[row][k]*W[col][k] + bias) * scale.
// ABF: A bf16 (else fp32, converted inline). W always fp32, converted inline.
// OBF: bf16 out.  BROW: bias by row.  OSTR: output row stride.
// 128x128 tile, BK=32, 4 waves (2x2), 4x4 MFMA tiles per wave.
// ---------------------------------------------------------------------------
struct GemmArgs { const void* A; const float* W; const float* bias; void* out; float scale; };

template<int ABF, int OBF, int BROW, int OSTR>
__global__ __launch_bounds__(256) void gemm_bt_t(GemmArgs g0, GemmArgs g1)
{
    GemmArgs g = (blockIdx.z == 0) ? g0 : g1;
    const int tid = threadIdx.x;
    const int n0 = blockIdx.x * 128, m0 = blockIdx.y * 128;

    __shared__ alignas(16) unsigned short As[128 * 40];
    __shared__ alignas(16) unsigned short Ws[128 * 40];

    const int kc = tid & 7;
    const int r0 = tid >> 3;
    const int wave = tid >> 6, lane = tid & 63;
    const int wm = wave >> 1, wn = wave & 1;
    const int r16 = lane & 15, quad = lane >> 4;

    f32x4v acc[4][4];
#pragma unroll
    for (int mi = 0; mi < 4; ++mi)
#pragma unroll
        for (int ni = 0; ni < 4; ++ni)
            acc[mi][ni] = (f32x4v){0.f, 0.f, 0.f, 0.f};

    u16x4 apre[4], wpre[4];
    auto ldA = [&](int k0, int rr) -> u16x4 {
        const int r = r0 + rr * 32;
        if (ABF) {
            return *(const u16x4*)((const unsigned short*)g.A + (size_t)(m0 + r) * 512 + k0 + kc * 4);
        } else {
            const float4 av = *(const float4*)((const float*)g.A + (size_t)(m0 + r) * 512 + k0 + kc * 4);
            return (u16x4){ bf16u(av.x), bf16u(av.y), bf16u(av.z), bf16u(av.w) };
        }
    };
    auto ldW = [&](int k0, int rr) -> u16x4 {
        const int r = r0 + rr * 32;
        const float4 wv = *(const float4*)(g.W + (size_t)(n0 + r) * 512 + k0 + kc * 4);
        return (u16x4){ bf16u(wv.x), bf16u(wv.y), bf16u(wv.z), bf16u(wv.w) };
    };
#pragma unroll
    for (int rr = 0; rr < 4; ++rr) { apre[rr] = ldA(0, rr); wpre[rr] = ldW(0, rr); }

    for (int k0 = 0; k0 < 512; k0 += 32) {
        __syncthreads();   // previous iteration's LDS reads complete
#pragma unroll
        for (int rr = 0; rr < 4; ++rr) {
            const int r = r0 + rr * 32;
            *(u16x4*)(As + r * 40 + kc * 4) = apre[rr];
            *(u16x4*)(Ws + r * 40 + kc * 4) = wpre[rr];
        }
        __syncthreads();
        if (k0 < 480) {    // prefetch next tile; latency overlaps the MFMAs below
#pragma unroll
            for (int rr = 0; rr < 4; ++rr) { apre[rr] = ldA(k0 + 32, rr); wpre[rr] = ldW(k0 + 32, rr); }
        }

        bf16x8 af[4], bfr[4];
#pragma unroll
        for (int mi = 0; mi < 4; ++mi)
            af[mi] = *(const bf16x8*)(As + (wm * 64 + mi * 16 + r16) * 40 + quad * 8);
#pragma unroll
        for (int ni = 0; ni < 4; ++ni)
            bfr[ni] = *(const bf16x8*)(Ws + (wn * 64 + ni * 16 + r16) * 40 + quad * 8);
#pragma unroll
        for (int mi = 0; mi < 4; ++mi)
#pragma unroll
            for (int ni = 0; ni < 4; ++ni)
                acc[mi][ni] = __builtin_amdgcn_mfma_f32_16x16x32_bf16(af[mi], bfr[ni], acc[mi][ni], 0, 0, 0);
    }

#pragma unroll
    for (int ni = 0; ni < 4; ++ni) {
        const int col = n0 + wn * 64 + ni * 16 + r16;
        const float bcol = BROW ? 0.f : g.bias[col];
#pragma unroll
        for (int mi = 0; mi < 4; ++mi) {
#pragma unroll
            for (int i = 0; i < 4; ++i) {
                const int row = m0 + wm * 64 + mi * 16 + quad * 4 + i;
                const float bv = BROW ? g.bias[row] : bcol;
                const float v = (acc[mi][ni][i] + bv) * g.scale;
                if (OBF) ((unsigned short*)g.out)[(size_t)row * OSTR + col] = bf16u(v);
                else     ((float*)g.out)[(size_t)row * OSTR + col] = v;
            }
        }
    }
}

// ---------------------------------------------------------------------------
// MFMA flash attention v4: ZERO barriers. One wave per block (16 q-rows);
// K and V^T fragments loaded directly from global (B-frag layout == global
// layout; L2 serves re-reads: K+V per (b,h) = 256KB << 4MB XCD L2). Only the
// per-wave P' C->A-layout round-trip uses LDS (within-wave DS ordering is
// hardware-guaranteed). grid: (64, 8, 4)  block: 64
// ---------------------------------------------------------------------------
#define APAD 72

__global__ __launch_bounds__(64) void attn_mfma4_kernel(
    const unsigned short* __restrict__ qp16, const unsigned short* __restrict__ kp16,
    const unsigned short* __restrict__ vtp16,
    const float* __restrict__ probs_q, const float* __restrict__ probs_k,
    const float* __restrict__ padding_mask, unsigned short* __restrict__ ao16)
{
    const int lane = threadIdx.x;
    const int r16 = lane & 15, quad = lane >> 4;
    const int b = blockIdx.z, h = blockIdx.y;
    const int qbase = blockIdx.x * 16;

    __shared__ alignas(16) unsigned short Ps[16 * APAD];

    bf16x8 qa0, qa1;
    {
        const unsigned short* qrow = qp16 + ((size_t)(b * NL + qbase + r16)) * ND + h * NDK;
        qa0 = *(const bf16x8*)(qrow + quad * 8);
        qa1 = *(const bf16x8*)(qrow + 32 + quad * 8);
    }
    float pq[4][8];
#pragma unroll
    for (int i = 0; i < 4; ++i) {
        const float* pr = probs_q + ((size_t)((b * NH + h) * NL + qbase + quad * 4 + i)) * NC;
        float4 a = ((const float4*)pr)[0], c = ((const float4*)pr)[1];
        pq[i][0] = a.x; pq[i][1] = a.y; pq[i][2] = a.z; pq[i][3] = a.w;
        pq[i][4] = c.x; pq[i][5] = c.y; pq[i][6] = c.z; pq[i][7] = c.w;
    }

    f32x4v oacc[4];
#pragma unroll
    for (int n = 0; n < 4; ++n) oacc[n] = (f32x4v){0.f, 0.f, 0.f, 0.f};
    float m_i[4] = {-1e30f, -1e30f, -1e30f, -1e30f};
    float l_i[4] = {0.f, 0.f, 0.f, 0.f};

    const unsigned short* kbase = kp16 + (size_t)b * NL * ND + h * NDK;
    const unsigned short* vbase = vtp16 + (size_t)(h * NDK) * (NB * NL) + b * NL;
    const float* pkb = probs_k + ((size_t)(b * NH + h)) * NL * NC;
    const float* pmb = padding_mask + b * NL;

    for (int kt = 0; kt < 16; ++kt) {
        const int key0 = kt * 64;

        // ---- K B-frags direct from global ----
        bf16x8 kb0[4], kb1[4];
#pragma unroll
        for (int t = 0; t < 4; ++t) {
            const unsigned short* kr = kbase + (size_t)(key0 + t * 16 + r16) * ND;
            kb0[t] = *(const bf16x8*)(kr + quad * 8);
            kb1[t] = *(const bf16x8*)(kr + 32 + quad * 8);
        }
        f32x4v sacc[4];
#pragma unroll
        for (int t = 0; t < 4; ++t) {
            sacc[t] = (f32x4v){0.f, 0.f, 0.f, 0.f};
            sacc[t] = __builtin_amdgcn_mfma_f32_16x16x32_bf16(qa0, kb0[t], sacc[t], 0, 0, 0);
            sacc[t] = __builtin_amdgcn_mfma_f32_16x16x32_bf16(qa1, kb1[t], sacc[t], 0, 0, 0);
        }

        // ---- sim (fp32: enters exponent x10000) + mask ----
        float sc[4][4], wgt[4][4];
#pragma unroll
        for (int t = 0; t < 4; ++t) {
            const int keyg = key0 + t * 16 + r16;
            const float4 p0 = *(const float4*)(pkb + (size_t)keyg * NC);
            const float4 p1 = *(const float4*)(pkb + (size_t)keyg * NC + 4);
            const float pmv = pmb[keyg];
#pragma unroll
            for (int i = 0; i < 4; ++i) {
                float sim = pq[i][0] * p0.x + pq[i][1] * p0.y + pq[i][2] * p0.z + pq[i][3] * p0.w
                          + pq[i][4] * p1.x + pq[i][5] * p1.y + pq[i][6] * p1.z + pq[i][7] * p1.w;
                float cm = 1.f - sim + pmv;
                cm = fminf(fmaxf(cm, 0.f), 1.f);
                sc[t][i] = sacc[t][i] - 10000.f * cm;
                wgt[t][i] = 1.f - cm;
            }
        }

        // ---- online softmax (row stats over the 16-lane quad group) ----
        float mx[4];
#pragma unroll
        for (int i = 0; i < 4; ++i)
            mx[i] = fmaxf(fmaxf(sc[0][i], sc[1][i]), fmaxf(sc[2][i], sc[3][i]));
#pragma unroll
        for (int o = 1; o < 16; o <<= 1) {
#pragma unroll
            for (int i = 0; i < 4; ++i) mx[i] = fmaxf(mx[i], __shfl_xor(mx[i], o));
        }
        float rr[4];
#pragma unroll
        for (int i = 0; i < 4; ++i) {
            const float mnew = fmaxf(m_i[i], mx[i]);
            rr[i] = __expf(m_i[i] - mnew);
            m_i[i] = mnew;
            l_i[i] *= rr[i];
        }
#pragma unroll
        for (int n = 0; n < 4; ++n) {
            oacc[n][0] *= rr[0]; oacc[n][1] *= rr[1];
            oacc[n][2] *= rr[2]; oacc[n][3] *= rr[3];
        }
        float lad[4] = {0.f, 0.f, 0.f, 0.f};
#pragma unroll
        for (int t = 0; t < 4; ++t) {
#pragma unroll
            for (int i = 0; i < 4; ++i) {
                const float p = __expf(sc[t][i] - m_i[i]);
                lad[i] += p;
                Ps[(quad * 4 + i) * APAD + t * 16 + r16] = bf16u(p * wgt[t][i]);
            }
        }
#pragma unroll
        for (int o = 1; o < 16; o <<= 1) {
#pragma unroll
            for (int i = 0; i < 4; ++i) lad[i] += __shfl_xor(lad[i], o);
        }
#pragma unroll
        for (int i = 0; i < 4; ++i) l_i[i] += lad[i];

        // ---- O += P' V  (A from Ps via LDS; V^T B-frags direct from global) ----
        bf16x8 pa0 = *(const bf16x8*)(Ps + r16 * APAD + quad * 8);
        bf16x8 pa1 = *(const bf16x8*)(Ps + r16 * APAD + 32 + quad * 8);
#pragma unroll
        for (int n = 0; n < 4; ++n) {
            const unsigned short* vr = vbase + (size_t)(n * 16 + r16) * (NB * NL) + key0;
            bf16x8 vb0 = *(const bf16x8*)(vr + quad * 8);
            bf16x8 vb1 = *(const bf16x8*)(vr + 32 + quad * 8);
            oacc[n] = __builtin_amdgcn_mfma_f32_16x16x32_bf16(pa0, vb0, oacc[n], 0, 0, 0);
            oacc[n] = __builtin_amdgcn_mfma_f32_16x16x32_bf16(pa1, vb1, oacc[n], 0, 0, 0);
        }
    }

    // ---- epilogue: O / l, bf16 out ----
#pragma unroll
    for (int i = 0; i < 4; ++i) {
        const float inv = 1.f / l_i[i];
        const int q = qbase + quad * 4 + i;
        unsigned short* orow = ao16 + ((size_t)(b * NL + q)) * ND + h * NDK;
#pragma unroll
        for (int n = 0; n < 4; ++n) orow[n * 16 + r16] = bf16u(oacc[n][i] * inv);
    }
}

// ---------------------------------------------------------------------------
// Finalize: reduce per-block partials -> kl_loss[b], div_loss[b].
// 1 block, 256 threads = 4 waves, one wave per b.
// ---------------------------------------------------------------------------
__global__ void finalize_kernel(const float* __restrict__ klp, const float* __restrict__ divp,
                                const float* __restrict__ Gp, float* __restrict__ out_tail)
{
    const int tid = threadIdx.x, b = tid >> 6, lane = tid & 63;

    float gsum = 0.f;
#pragma unroll
    for (int s = 0; s < 2; ++s)
#pragma unroll
        for (int h = 0; h < 8; ++h) {
            const int base = s * 256 + (b * 8 + h) * 8;
            float Ge = 0.f;
#pragma unroll
            for (int x = 0; x < 8; ++x) Ge += Gp[(size_t)(base + x) * 64 + lane];
            gsum = fmaf(Ge, Ge, gsum);
        }

    float klv = 0.f, dvv = 0.f;
#pragma unroll
    for (int rep = 0; rep < 2; ++rep) {
        const int lin = rep * 64 + lane;            // 0..127 -> (s, h, x)
        const int s = lin >> 6, rem = lin & 63, h = rem >> 3, x = rem & 7;
        const int idx = s * 256 + (b * 8 + h) * 8 + x;
        klv += klp[idx];
        dvv += divp[idx];
    }
#pragma unroll
    for (int o = 32; o > 0; o >>= 1) {
        gsum += __shfl_down(gsum, o);
        klv  += __shfl_down(klv, o);
        dvv  += __shfl_down(dvv, o);
    }
    if (lane == 0) {
        out_tail[b]     = klv * (1.0f / 8192.0f) + 2.0f * KL3_CONST;
        out_tail[4 + b] = (dvv + 0.75f * gsum) * (1.0f / 8388608.0f);
    }
}

// ---------------------------------------------------------------------------
extern "C" void kernel_launch(void* const* d_in, const int* in_sizes, int n_in,
                              void* d_out, int out_size, void* d_ws, size_t ws_size,
                              hipStream_t stream)
{
    const float* query        = (const float*)d_in[0];
    const float* key          = (const float*)d_in[1];
    const float* value        = (const float*)d_in[2];
    const float* padding_mask = (const float*)d_in[3];
    const float* Wq = (const float*)d_in[4];
    const float* bq = (const float*)d_in[5];
    const float* Wk = (const float*)d_in[6];
    const float* bk = (const float*)d_in[7];
    const float* Wv = (const float*)d_in[8];
    const float* bv = (const float*)d_in[9];
    const float* Wo = (const float*)d_in[10];
    const float* bo = (const float*)d_in[11];
    const float* tok_mu        = (const float*)d_in[12];
    const float* tok_log_var   = (const float*)d_in[13];
    const float* tok_log_prior = (const float*)d_in[14];

    float* ws = (float*)d_ws;
    const size_t NMAT = (size_t)NB * NL * ND;        // 2097152 elements
    const size_t NH16 = NMAT / 2;                    // bf16 matrix in float-slots
    // buf0: q16i (dead after QK gemm) -> reused as ao16
    // buf1: k16i (dead after QK gemm) -> reused as vtp16 [512][4096]
    unsigned short* q16i  = (unsigned short*)ws;
    unsigned short* ao16  = q16i;
    unsigned short* k16i  = (unsigned short*)(ws + NH16);
    unsigned short* vtp16 = k16i;
    unsigned short* qp16  = (unsigned short*)(ws + 2 * NH16);
    unsigned short* kp16  = (unsigned short*)(ws + 3 * NH16);
    float* probs_q = ws + 4 * NH16;                  // 262144 floats each
    float* probs_k = probs_q + (size_t)NB * NH * NL * NC;
    float* klp     = probs_k + (size_t)NB * NH * NL * NC;   // 512
    float* divp    = klp + 512;                              // 512
    float* Gp      = divp + 512;                             // 512*64

    cluster_kernel<<<dim3(8, NB * NH, 2), 128, 0, stream>>>(
        query, key, tok_mu, tok_log_var, tok_log_prior,
        probs_q, probs_k, q16i, k16i, klp, divp, Gp);

    // Q,K projections: out = (x @ W^T + b) [*1/8 for Q], bf16 out
    GemmArgs gq{q16i, Wq, bq, qp16, 0.125f};
    GemmArgs gk{k16i, Wk, bk, kp16, 1.f};
    gemm_bt_t<1, 1, 0, 512><<<dim3(4, 32, 2), 256, 0, stream>>>(gq, gk);

    // V^T projection: vt[dim][tok] = Wv . value^T + bv[dim]  (bias by row)
    GemmArgs gvt{Wv, value, bv, vtp16, 1.f};
    gemm_bt_t<0, 1, 1, 4096><<<dim3(32, 4, 1), 256, 0, stream>>>(gvt, gvt);

    attn_mfma4_kernel<<<dim3(64, NH, NB), 64, 0, stream>>>(
        qp16, kp16, vtp16, probs_q, probs_k, padding_mask, ao16);

    GemmArgs go{ao16, Wo, bo, d_out, 1.f};
    gemm_bt_t<1, 0, 0, 512><<<dim3(4, 32, 1), 256, 0, stream>>>(go, go);

    finalize_kernel<<<1, 256, 0, stream>>>(klp, divp, Gp, (float*)d_out + NMAT);
}